// Round 1
// baseline (1373.820 us; speedup 1.0000x reference)
//
#include <hip/hip_runtime.h>

typedef float  f32x4 __attribute__((ext_vector_type(4)));
typedef short  s16x8 __attribute__((ext_vector_type(8)));
typedef unsigned short u16;
typedef unsigned short u16x8 __attribute__((ext_vector_type(8)));

#define MFMA __builtin_amdgcn_mfma_f32_16x16x32_bf16

#define SEQ 4096
#define DIM 1024
#define NB  4

__device__ inline u16 f2bf(float f) {
  union { float f; unsigned u; } v; v.f = f;
  unsigned r = v.u + 0x7FFFu + ((v.u >> 16) & 1u);
  return (u16)(r >> 16);
}

// ---------- W [e][h] f32 -> Wt [h][e] bf16 ----------
__global__ __launch_bounds__(256) void wcvt(const float* __restrict__ W, u16* __restrict__ Wt) {
  __shared__ float tile[32][33];
  int t = threadIdx.x, tx = t & 31, ty = t >> 5;
  int e0 = blockIdx.y * 32, h0 = blockIdx.x * 32;
#pragma unroll
  for (int i = 0; i < 4; ++i)
    tile[ty + i * 8][tx] = W[(size_t)(e0 + ty + i * 8) * DIM + h0 + tx];
  __syncthreads();
#pragma unroll
  for (int i = 0; i < 4; ++i)
    Wt[(size_t)(h0 + ty + i * 8) * DIM + e0 + tx] = f2bf(tile[tx][ty + i * 8]);
}

// ---------- V [b][s][h] bf16 -> Vt [b][h][s] bf16 ----------
__global__ __launch_bounds__(256) void vtrans(const u16* __restrict__ V, u16* __restrict__ Vt) {
  __shared__ u16 tile[32][34];
  int t = threadIdx.x, tx = t & 31, ty = t >> 5;
  int b = blockIdx.z;
  int s0 = blockIdx.x * 32, h0 = blockIdx.y * 32;
  const u16* Vb = V + (size_t)b * SEQ * DIM;
  u16* Vtb = Vt + (size_t)b * DIM * SEQ;
#pragma unroll
  for (int i = 0; i < 4; ++i)
    tile[ty + i * 8][tx] = Vb[(size_t)(s0 + ty + i * 8) * DIM + h0 + tx];
  __syncthreads();
#pragma unroll
  for (int i = 0; i < 4; ++i)
    Vtb[(size_t)(h0 + ty + i * 8) * SEQ + s0 + tx] = tile[tx][ty + i * 8];
}

// ---------- GEMM: C[m][n] = X[m][k] * Wt[n][k]^T, X fp32, Wt/C bf16 ----------
// 128x128 tile, BK=32, 4 waves (2x2), each wave 64x64, padded LDS stride 40.
__global__ __launch_bounds__(256, 2) void gemm_xw(const float* __restrict__ X,
                                                  const u16* __restrict__ Wt,
                                                  u16* __restrict__ C) {
  const int K = DIM, N = DIM;
  __shared__ u16 As[128 * 40];
  __shared__ u16 Bs[128 * 40];
  int m0 = blockIdx.y * 128, n0 = blockIdx.x * 128;
  int t = threadIdx.x, lane = t & 63, w = t >> 6;
  int wr = w >> 1, wc = w & 1;
  int l16 = lane & 15, lh = lane >> 4;
  f32x4 acc[4][4] = {};
  for (int kb = 0; kb < K; kb += 32) {
    __syncthreads();
#pragma unroll
    for (int i = 0; i < 2; ++i) {
      int c = t + i * 256, row = c >> 2, cc = c & 3;
      // A: fp32 -> bf16 on the fly
      const f32x4* src = (const f32x4*)(X + (size_t)(m0 + row) * K + kb + cc * 8);
      f32x4 v0 = src[0], v1 = src[1];
      u16x8 p;
      p[0] = f2bf(v0[0]); p[1] = f2bf(v0[1]); p[2] = f2bf(v0[2]); p[3] = f2bf(v0[3]);
      p[4] = f2bf(v1[0]); p[5] = f2bf(v1[1]); p[6] = f2bf(v1[2]); p[7] = f2bf(v1[3]);
      *(u16x8*)&As[row * 40 + cc * 8] = p;
      // B: already bf16
      u16x8 bv = *(const u16x8*)(Wt + (size_t)(n0 + row) * K + kb + cc * 8);
      *(u16x8*)&Bs[row * 40 + cc * 8] = bv;
    }
    __syncthreads();
    s16x8 af[4], bfr[4];
#pragma unroll
    for (int mt = 0; mt < 4; ++mt)
      af[mt] = *(const s16x8*)&As[(wr * 64 + mt * 16 + l16) * 40 + lh * 8];
#pragma unroll
    for (int nt = 0; nt < 4; ++nt)
      bfr[nt] = *(const s16x8*)&Bs[(wc * 64 + nt * 16 + l16) * 40 + lh * 8];
#pragma unroll
    for (int mt = 0; mt < 4; ++mt)
#pragma unroll
      for (int nt = 0; nt < 4; ++nt)
        acc[mt][nt] = MFMA(af[mt], bfr[nt], acc[mt][nt], 0, 0, 0);
  }
#pragma unroll
  for (int mt = 0; mt < 4; ++mt)
#pragma unroll
    for (int nt = 0; nt < 4; ++nt)
#pragma unroll
      for (int r = 0; r < 4; ++r) {
        int row = m0 + wr * 64 + mt * 16 + lh * 4 + r;
        int col = n0 + wc * 64 + nt * 16 + l16;
        C[(size_t)row * N + col] = f2bf(acc[mt][nt][r]);
      }
}

// ---------- Flash attention (causal), QB=32, KB=32, 8 waves split-D ----------
// wave w owns D-slice [128w, 128w+128): QK^T partial over its slice -> LDS reduce
// -> wave-parallel online softmax -> PV into O[32 x 128w..] accumulator.
__global__ __launch_bounds__(512, 2) void attn(const u16* __restrict__ Q,
                                               const u16* __restrict__ Kg,
                                               const u16* __restrict__ Vt,
                                               float* __restrict__ O) {
  __shared__ float Sp[8][32][34];
  __shared__ u16 Pl[32][40];
  __shared__ float alpha_l[32];
  __shared__ float lsum_l[32];

  int b = blockIdx.y;
  int qt = (int)(gridDim.x - 1 - blockIdx.x);  // big tiles launch first
  int q0 = qt * 32;
  int t = threadIdx.x, lane = t & 63, w = t >> 6;
  int myrow = t >> 4, mycol = t & 15;
  int l16 = lane & 15, lh = lane >> 4;

  const u16* Qb = Q  + (size_t)b * SEQ * DIM;
  const u16* Kb = Kg + (size_t)b * SEQ * DIM;
  const u16* Vb = Vt + (size_t)b * DIM * SEQ;
  float*     Ob = O  + (size_t)b * SEQ * DIM;

  // hoist Q fragments: rows q0..q0+31, cols w*128..+128
  s16x8 qf[2][4];
#pragma unroll
  for (int mt = 0; mt < 2; ++mt)
#pragma unroll
    for (int kc = 0; kc < 4; ++kc)
      qf[mt][kc] = *(const s16x8*)(Qb + (size_t)(q0 + mt * 16 + l16) * DIM + w * 128 + kc * 32 + lh * 8);

  f32x4 acc[2][8] = {};
  float m_run = -1e30f, l_run = 0.f;

  int nkb = qt + 1;
  for (int kb = 0; kb < nkb; ++kb) {
    int k0 = kb * 32;
    // ---- QK^T partial over this wave's 128-dim slice ----
    f32x4 sf[2][2] = {};
#pragma unroll
    for (int kc = 0; kc < 4; ++kc) {
      s16x8 kf0 = *(const s16x8*)(Kb + (size_t)(k0 + l16)      * DIM + w * 128 + kc * 32 + lh * 8);
      s16x8 kf1 = *(const s16x8*)(Kb + (size_t)(k0 + 16 + l16) * DIM + w * 128 + kc * 32 + lh * 8);
      sf[0][0] = MFMA(qf[0][kc], kf0, sf[0][0], 0, 0, 0);
      sf[0][1] = MFMA(qf[0][kc], kf1, sf[0][1], 0, 0, 0);
      sf[1][0] = MFMA(qf[1][kc], kf0, sf[1][0], 0, 0, 0);
      sf[1][1] = MFMA(qf[1][kc], kf1, sf[1][1], 0, 0, 0);
    }
#pragma unroll
    for (int mt = 0; mt < 2; ++mt)
#pragma unroll
      for (int nt = 0; nt < 2; ++nt)
#pragma unroll
        for (int r = 0; r < 4; ++r)
          Sp[w][mt * 16 + lh * 4 + r][nt * 16 + l16] = sf[mt][nt][r];
    __syncthreads();

    // ---- reduce 8 partials + online softmax (thread t owns row t>>4, cols t&15 / +16) ----
    float s0 = 0.f, s1 = 0.f;
#pragma unroll
    for (int wv = 0; wv < 8; ++wv) { s0 += Sp[wv][myrow][mycol]; s1 += Sp[wv][myrow][mycol + 16]; }
    s0 *= 0.03125f; s1 *= 0.03125f;   // 1/sqrt(1024)
    if (kb == qt) {                   // diagonal block causal mask
      if (mycol      > myrow) s0 = -1e30f;
      if (mycol + 16 > myrow) s1 = -1e30f;
    }
    float mb = fmaxf(s0, s1);
#pragma unroll
    for (int off = 1; off < 16; off <<= 1) mb = fmaxf(mb, __shfl_xor(mb, off, 16));
    float m_new = fmaxf(m_run, mb);
    float al = __expf(m_run - m_new);
    float p0 = __expf(s0 - m_new);
    float p1 = __expf(s1 - m_new);
    float lb = p0 + p1;
#pragma unroll
    for (int off = 1; off < 16; off <<= 1) lb += __shfl_xor(lb, off, 16);
    l_run = l_run * al + lb;
    m_run = m_new;
    Pl[myrow][mycol]      = f2bf(p0);
    Pl[myrow][mycol + 16] = f2bf(p1);
    if (mycol == 0) alpha_l[myrow] = al;
    __syncthreads();

    // ---- rescale O, then PV over this wave's 128 output cols ----
    float a0[4], a1[4];
#pragma unroll
    for (int r = 0; r < 4; ++r) { a0[r] = alpha_l[lh * 4 + r]; a1[r] = alpha_l[16 + lh * 4 + r]; }
#pragma unroll
    for (int nt = 0; nt < 8; ++nt)
#pragma unroll
      for (int r = 0; r < 4; ++r) { acc[0][nt][r] *= a0[r]; acc[1][nt][r] *= a1[r]; }

    s16x8 pf0 = *(const s16x8*)&Pl[l16][lh * 8];
    s16x8 pf1 = *(const s16x8*)&Pl[16 + l16][lh * 8];
#pragma unroll
    for (int nt = 0; nt < 8; ++nt) {
      s16x8 vf = *(const s16x8*)(Vb + (size_t)(w * 128 + nt * 16 + l16) * SEQ + k0 + lh * 8);
      acc[0][nt] = MFMA(pf0, vf, acc[0][nt], 0, 0, 0);
      acc[1][nt] = MFMA(pf1, vf, acc[1][nt], 0, 0, 0);
    }
    // no trailing barrier needed: next iter's Sp writes are fenced by the
    // next __syncthreads() before any thread's Pl/alpha re-write.
  }

  // ---- epilogue: normalize by l and store fp32 ----
  if (mycol == 0) lsum_l[myrow] = l_run;
  __syncthreads();
  float li0[4], li1[4];
#pragma unroll
  for (int r = 0; r < 4; ++r) {
    li0[r] = 1.f / lsum_l[lh * 4 + r];
    li1[r] = 1.f / lsum_l[16 + lh * 4 + r];
  }
#pragma unroll
  for (int nt = 0; nt < 8; ++nt)
#pragma unroll
    for (int r = 0; r < 4; ++r) {
      Ob[(size_t)(q0 + lh * 4 + r)      * DIM + w * 128 + nt * 16 + l16] = acc[0][nt][r] * li0[r];
      Ob[(size_t)(q0 + 16 + lh * 4 + r) * DIM + w * 128 + nt * 16 + l16] = acc[1][nt][r] * li1[r];
    }
}

extern "C" void kernel_launch(void* const* d_in, const int* in_sizes, int n_in,
                              void* d_out, int out_size, void* d_ws, size_t ws_size,
                              hipStream_t stream) {
  const float* x  = (const float*)d_in[0];
  const float* Wq = (const float*)d_in[1];
  const float* Wk = (const float*)d_in[2];
  const float* Wv = (const float*)d_in[3];
  float* out = (float*)d_out;

  // ws layout (bf16 elements): Wt q/k/v (3 x 1M), then Q, K, V, Vt (4 x 16.7M) = ~134 MB
  char* ws = (char*)d_ws;
  u16* Wtq = (u16*)ws;
  u16* Wtk = Wtq + (size_t)DIM * DIM;
  u16* Wtv = Wtk + (size_t)DIM * DIM;
  u16* Qb  = (u16*)(ws + (size_t)3 * DIM * DIM * 2);
  u16* Kb  = Qb + (size_t)NB * SEQ * DIM;
  u16* Vb  = Kb + (size_t)NB * SEQ * DIM;
  u16* Vtb = Vb + (size_t)NB * SEQ * DIM;

  wcvt<<<dim3(32, 32), dim3(256), 0, stream>>>(Wq, Wtq);
  wcvt<<<dim3(32, 32), dim3(256), 0, stream>>>(Wk, Wtk);
  wcvt<<<dim3(32, 32), dim3(256), 0, stream>>>(Wv, Wtv);

  gemm_xw<<<dim3(8, 128), dim3(256), 0, stream>>>(x, Wtq, Qb);
  gemm_xw<<<dim3(8, 128), dim3(256), 0, stream>>>(x, Wtk, Kb);
  gemm_xw<<<dim3(8, 128), dim3(256), 0, stream>>>(x, Wtv, Vb);

  vtrans<<<dim3(128, 32, 4), dim3(256), 0, stream>>>(Vb, Vtb);

  attn<<<dim3(128, 4), dim3(512), 0, stream>>>(Qb, Kb, Vtb, out);
}

// Round 4
// 813.667 us; speedup vs baseline: 1.6884x; 1.6884x over previous
//
#include <hip/hip_runtime.h>

typedef float  f32x4 __attribute__((ext_vector_type(4)));
typedef short  s16x8 __attribute__((ext_vector_type(8)));
typedef unsigned short u16;
typedef unsigned short u16x8 __attribute__((ext_vector_type(8)));

#define MFMA __builtin_amdgcn_mfma_f32_16x16x32_bf16

#define SEQ 4096
#define DIM 1024
#define NB  4

__device__ inline u16 f2bf(float f) {
  union { float f; unsigned u; } v; v.f = f;
  unsigned r = v.u + 0x7FFFu + ((v.u >> 16) & 1u);
  return (u16)(r >> 16);
}

// ---------- x f32 -> bf16, vectorized ----------
__global__ __launch_bounds__(256) void xcvt(const float* __restrict__ X, u16* __restrict__ X16) {
  size_t i = ((size_t)blockIdx.x * 256 + threadIdx.x) * 8;
  f32x4 a = *(const f32x4*)(X + i);
  f32x4 b = *(const f32x4*)(X + i + 4);
  u16x8 p;
  p[0] = f2bf(a[0]); p[1] = f2bf(a[1]); p[2] = f2bf(a[2]); p[3] = f2bf(a[3]);
  p[4] = f2bf(b[0]); p[5] = f2bf(b[1]); p[6] = f2bf(b[2]); p[7] = f2bf(b[3]);
  *(u16x8*)(X16 + i) = p;
}

// ---------- W [e][h] f32 -> Wt [h][e] bf16 ----------
__global__ __launch_bounds__(256) void wcvt(const float* __restrict__ W, u16* __restrict__ Wt) {
  __shared__ float tile[32][33];
  int t = threadIdx.x, tx = t & 31, ty = t >> 5;
  int e0 = blockIdx.y * 32, h0 = blockIdx.x * 32;
#pragma unroll
  for (int i = 0; i < 4; ++i)
    tile[ty + i * 8][tx] = W[(size_t)(e0 + ty + i * 8) * DIM + h0 + tx];
  __syncthreads();
#pragma unroll
  for (int i = 0; i < 4; ++i)
    Wt[(size_t)(h0 + ty + i * 8) * DIM + e0 + tx] = f2bf(tile[tx][ty + i * 8]);
}

// ---------- V [b][s][h] bf16 -> Vt [b][h][s] bf16 ----------
__global__ __launch_bounds__(256) void vtrans(const u16* __restrict__ V, u16* __restrict__ Vt) {
  __shared__ u16 tile[32][34];
  int t = threadIdx.x, tx = t & 31, ty = t >> 5;
  int b = blockIdx.z;
  int s0 = blockIdx.x * 32, h0 = blockIdx.y * 32;
  const u16* Vb = V + (size_t)b * SEQ * DIM;
  u16* Vtb = Vt + (size_t)b * DIM * SEQ;
#pragma unroll
  for (int i = 0; i < 4; ++i)
    tile[ty + i * 8][tx] = Vb[(size_t)(s0 + ty + i * 8) * DIM + h0 + tx];
  __syncthreads();
#pragma unroll
  for (int i = 0; i < 4; ++i)
    Vtb[(size_t)(h0 + ty + i * 8) * SEQ + s0 + tx] = tile[tx][ty + i * 8];
}

// ---------- GEMM: C[m][n] = X16[m][k] * Wt[n][k]^T, all bf16, f32 acc ----------
// 128x128 tile, BK=32, 4 waves (2x2), each wave 64x64, padded LDS stride 40.
__global__ __launch_bounds__(256, 2) void gemm_xw(const u16* __restrict__ X16,
                                                  const u16* __restrict__ Wt,
                                                  u16* __restrict__ C) {
  const int K = DIM, N = DIM;
  __shared__ u16 As[128 * 40];
  __shared__ u16 Bs[128 * 40];
  int m0 = blockIdx.y * 128, n0 = blockIdx.x * 128;
  int t = threadIdx.x, lane = t & 63, w = t >> 6;
  int wr = w >> 1, wc = w & 1;
  int l16 = lane & 15, lh = lane >> 4;
  f32x4 acc[4][4] = {};
  for (int kb = 0; kb < K; kb += 32) {
    __syncthreads();
#pragma unroll
    for (int i = 0; i < 2; ++i) {
      int c = t + i * 256, row = c >> 2, cc = c & 3;
      *(u16x8*)&As[row * 40 + cc * 8] = *(const u16x8*)(X16 + (size_t)(m0 + row) * K + kb + cc * 8);
      *(u16x8*)&Bs[row * 40 + cc * 8] = *(const u16x8*)(Wt  + (size_t)(n0 + row) * K + kb + cc * 8);
    }
    __syncthreads();
    s16x8 af[4], bfr[4];
#pragma unroll
    for (int mt = 0; mt < 4; ++mt)
      af[mt] = *(const s16x8*)&As[(wr * 64 + mt * 16 + l16) * 40 + lh * 8];
#pragma unroll
    for (int nt = 0; nt < 4; ++nt)
      bfr[nt] = *(const s16x8*)&Bs[(wc * 64 + nt * 16 + l16) * 40 + lh * 8];
#pragma unroll
    for (int mt = 0; mt < 4; ++mt)
#pragma unroll
      for (int nt = 0; nt < 4; ++nt)
        acc[mt][nt] = MFMA(af[mt], bfr[nt], acc[mt][nt], 0, 0, 0);
  }
#pragma unroll
  for (int mt = 0; mt < 4; ++mt)
#pragma unroll
    for (int nt = 0; nt < 4; ++nt)
#pragma unroll
      for (int r = 0; r < 4; ++r) {
        int row = m0 + wr * 64 + mt * 16 + lh * 4 + r;
        int col = n0 + wc * 64 + nt * 16 + l16;
        C[(size_t)row * N + col] = f2bf(acc[mt][nt][r]);
      }
}

// ---------- Flash attention (causal), QB=32, KB=128, 8 waves ----------
// QK^T: hybrid split — wave (d,kg): d owns 256 of 1024 dims (Q frags in regs),
// kg owns 64 of 128 keys. 4 partials reduced through transposed LDS scores.
// PV: split-D — wave w owns output h-slice [128w,128w+128).
// Load balance: each block serially processes q-tiles {p, 127-p} = 33 steps.
__global__ __launch_bounds__(512, 2) void attn(const u16* __restrict__ Q,
                                               const u16* __restrict__ Kg,
                                               const u16* __restrict__ Vt,
                                               float* __restrict__ O) {
  __shared__ float Sp[4][128][36];   // [d-quarter][key][q-row], transposed scores
  __shared__ u16   Pl[32][136];      // [q-row][key] bf16 probabilities
  __shared__ float alpha_l[32];
  __shared__ float lsum_l[32];

  int bid = blockIdx.x;
  int batch = (bid & 7) >> 1;                 // batch -> XCD-pair grouping
  int pi = ((bid >> 3) << 1) | (bid & 1);     // 0..63 pair index

  int t = threadIdx.x, lane = t & 63, w = t >> 6;
  int d = w >> 1, kg = w & 1;
  int l16 = lane & 15, lh = lane >> 4;
  int myrow = t >> 4, mycol = t & 15;

  const u16* Qb = Q  + (size_t)batch * SEQ * DIM;
  const u16* Kb = Kg + (size_t)batch * SEQ * DIM;
  const u16* Vb = Vt + (size_t)batch * DIM * SEQ;
  float*     Ob = O  + (size_t)batch * SEQ * DIM;

#pragma unroll
  for (int tile = 0; tile < 2; ++tile) {
    int qt = tile ? (127 - pi) : pi;
    int q0 = qt * 32;
    int nkb = (qt >> 2) + 1;

    // Q fragments resident in regs: rows q0+mt*16+l16, dims d*256 + kc*32 + lh*8
    s16x8 qf[2][8];
#pragma unroll
    for (int mt = 0; mt < 2; ++mt)
#pragma unroll
      for (int kc = 0; kc < 8; ++kc)
        qf[mt][kc] = *(const s16x8*)(Qb + (size_t)(q0 + mt * 16 + l16) * DIM + d * 256 + kc * 32 + lh * 8);

    f32x4 acc[2][8] = {};
    float m_run = -1e30f, l_run = 0.f;

    for (int kb = 0; kb < nkb; ++kb) {
      int k0 = kb * 128;
      // ---- P1: QK^T partial (d-quarter of dims, kg's 64 keys) ----
      f32x4 sf[2][4] = {};
#pragma unroll
      for (int kc = 0; kc < 8; ++kc)
#pragma unroll
        for (int nt = 0; nt < 4; ++nt) {
          s16x8 kf = *(const s16x8*)(Kb + (size_t)(k0 + kg * 64 + nt * 16 + l16) * DIM + d * 256 + kc * 32 + lh * 8);
          sf[0][nt] = MFMA(qf[0][kc], kf, sf[0][nt], 0, 0, 0);
          sf[1][nt] = MFMA(qf[1][kc], kf, sf[1][nt], 0, 0, 0);
        }
#pragma unroll
      for (int mt = 0; mt < 2; ++mt)
#pragma unroll
        for (int nt = 0; nt < 4; ++nt)
          *(f32x4*)&Sp[d][kg * 64 + nt * 16 + l16][mt * 16 + lh * 4] = sf[mt][nt];
      __syncthreads();

      // ---- P2: reduce 4 partials + online softmax ----
      float s[8], p[8];
#pragma unroll
      for (int j = 0; j < 8; ++j) {
        int c = mycol + 16 * j;
        float v = Sp[0][c][myrow] + Sp[1][c][myrow] + Sp[2][c][myrow] + Sp[3][c][myrow];
        v *= 0.03125f;                              // 1/sqrt(1024)
        s[j] = (k0 + c > q0 + myrow) ? -1e30f : v;  // causal mask
      }
      float mb = s[0];
#pragma unroll
      for (int j = 1; j < 8; ++j) mb = fmaxf(mb, s[j]);
#pragma unroll
      for (int off = 1; off < 16; off <<= 1) mb = fmaxf(mb, __shfl_xor(mb, off, 16));
      float m_new = fmaxf(m_run, mb);
      float al = __expf(m_run - m_new);
      float lb = 0.f;
#pragma unroll
      for (int j = 0; j < 8; ++j) { p[j] = __expf(s[j] - m_new); lb += p[j]; }
#pragma unroll
      for (int off = 1; off < 16; off <<= 1) lb += __shfl_xor(lb, off, 16);
      l_run = l_run * al + lb;
      m_run = m_new;
#pragma unroll
      for (int j = 0; j < 8; ++j) Pl[myrow][mycol + 16 * j] = f2bf(p[j]);
      if (mycol == 0) alpha_l[myrow] = al;
      __syncthreads();

      // ---- P3: rescale O, PV over wave's 128 h-cols ----
      float a0[4], a1[4];
#pragma unroll
      for (int r = 0; r < 4; ++r) { a0[r] = alpha_l[lh * 4 + r]; a1[r] = alpha_l[16 + lh * 4 + r]; }
#pragma unroll
      for (int nt = 0; nt < 8; ++nt)
#pragma unroll
        for (int r = 0; r < 4; ++r) { acc[0][nt][r] *= a0[r]; acc[1][nt][r] *= a1[r]; }
      s16x8 pf[2][4];
#pragma unroll
      for (int mt = 0; mt < 2; ++mt)
#pragma unroll
        for (int kc = 0; kc < 4; ++kc)
          pf[mt][kc] = *(const s16x8*)&Pl[mt * 16 + l16][kc * 32 + lh * 8];
#pragma unroll
      for (int kc = 0; kc < 4; ++kc)
#pragma unroll
        for (int nt = 0; nt < 8; ++nt) {
          s16x8 vf = *(const s16x8*)(Vb + (size_t)(w * 128 + nt * 16 + l16) * SEQ + k0 + kc * 32 + lh * 8);
          acc[0][nt] = MFMA(pf[0][kc], vf, acc[0][nt], 0, 0, 0);
          acc[1][nt] = MFMA(pf[1][kc], vf, acc[1][nt], 0, 0, 0);
        }
    }

    // ---- epilogue: normalize by l and store fp32 ----
    if (mycol == 0) lsum_l[myrow] = l_run;
    __syncthreads();
    float li0[4], li1[4];
#pragma unroll
    for (int r = 0; r < 4; ++r) {
      li0[r] = 1.f / lsum_l[lh * 4 + r];
      li1[r] = 1.f / lsum_l[16 + lh * 4 + r];
    }
#pragma unroll
    for (int nt = 0; nt < 8; ++nt)
#pragma unroll
      for (int r = 0; r < 4; ++r) {
        Ob[(size_t)(q0 + lh * 4 + r)      * DIM + w * 128 + nt * 16 + l16] = acc[0][nt][r] * li0[r];
        Ob[(size_t)(q0 + 16 + lh * 4 + r) * DIM + w * 128 + nt * 16 + l16] = acc[1][nt][r] * li1[r];
      }
    __syncthreads();
  }
}

extern "C" void kernel_launch(void* const* d_in, const int* in_sizes, int n_in,
                              void* d_out, int out_size, void* d_ws, size_t ws_size,
                              hipStream_t stream) {
  const float* x  = (const float*)d_in[0];
  const float* Wq = (const float*)d_in[1];
  const float* Wk = (const float*)d_in[2];
  const float* Wv = (const float*)d_in[3];
  float* out = (float*)d_out;

  // ws layout (bf16 elems): Wtq/Wtk/Wtv (3x1M), X16 (16.7M, later aliased by Vt),
  // Q, K, V (3x16.7M). Total = 140.5 MB (same footprint as round 1).
  u16* Wtq = (u16*)d_ws;
  u16* Wtk = Wtq + (size_t)DIM * DIM;
  u16* Wtv = Wtk + (size_t)DIM * DIM;
  u16* X16 = Wtv + (size_t)DIM * DIM;
  u16* Qb  = X16 + (size_t)NB * SEQ * DIM;
  u16* Kb  = Qb  + (size_t)NB * SEQ * DIM;
  u16* Vb  = Kb  + (size_t)NB * SEQ * DIM;
  u16* Vtb = X16;  // x16 dead after the GEMMs; reuse for V^T

  xcvt<<<dim3(8192), dim3(256), 0, stream>>>(x, X16);

  wcvt<<<dim3(32, 32), dim3(256), 0, stream>>>(Wq, Wtq);
  wcvt<<<dim3(32, 32), dim3(256), 0, stream>>>(Wk, Wtk);
  wcvt<<<dim3(32, 32), dim3(256), 0, stream>>>(Wv, Wtv);

  gemm_xw<<<dim3(8, 128), dim3(256), 0, stream>>>(X16, Wtq, Qb);
  gemm_xw<<<dim3(8, 128), dim3(256), 0, stream>>>(X16, Wtk, Kb);
  gemm_xw<<<dim3(8, 128), dim3(256), 0, stream>>>(X16, Wtv, Vb);

  vtrans<<<dim3(128, 32, 4), dim3(256), 0, stream>>>(Vb, Vtb);

  attn<<<dim3(256), dim3(512), 0, stream>>>(Qb, Kb, Vtb, out);
}